// Round 18
// baseline (1044.611 us; speedup 1.0000x reference)
//
#include <hip/hip_runtime.h>

typedef __attribute__((ext_vector_type(8))) short bfv8;
typedef __attribute__((ext_vector_type(4))) float f32x4;
typedef __attribute__((ext_vector_type(4))) unsigned short usv4;

typedef __attribute__((address_space(1))) const void gvoid;
typedef __attribute__((address_space(3))) void lvoid;
__device__ __forceinline__ void gload16(const void* g, void* l) {
  __builtin_amdgcn_global_load_lds((gvoid*)g, (lvoid*)l, 16, 0, 0);
}

__device__ __forceinline__ float bf2f(unsigned short u) {
  union { unsigned int i; float f; } c; c.i = ((unsigned int)u) << 16; return c.f;
}
__device__ __forceinline__ unsigned short f2bf(float f) {
  union { float f; unsigned int i; } c; c.f = f;
  unsigned int r = c.i + 0x7FFFu + ((c.i >> 16) & 1u);
  return (unsigned short)(r >> 16);
}
// tanh-form gelu via hw exp+rcp (max dev from erf-gelu ~5e-4)
__device__ __forceinline__ float gelu_(float x) {
  float z2 = 1.5957691216057308f * x * __builtin_fmaf(0.044715f, x * x, 1.0f);
  float e = __expf(z2);
  float t = __builtin_amdgcn_rcpf(e + 1.0f);
  return x - x * t;
}
__device__ __forceinline__ int div9(int col) {
  return (int)(__umulhi((unsigned)col, 954437177u) >> 1);
}

#define CHP 132   // big-kernel epilogue LDS channel stride (u16)
#define CHP2 66   // gemm2 kernel epilogue stride

// ---- weight prep ------------------------------------------------------------
__global__ void k_prep(const float* c1w, const float* c2w, const float* c3w,
                       const float* outw, unsigned short* W1b, unsigned short* W2t,
                       unsigned short* W3b, float* OWt) {
  int i = blockIdx.x * 256 + threadIdx.x;
  if (i < 262144) { W1b[i] = f2bf(c1w[i]); return; }
  i -= 262144;
  if (i < 655360) {   // W2t[l][t][o][ii] = c2w[l][o][ii][t]
    int ii = i & 255, o = (i >> 8) & 255, rest = i >> 16;
    int t = rest % 5, l = rest / 5;
    W2t[i] = f2bf(c2w[(((l * 256 + o) << 8) + ii) * 5 + t]);
    return;
  }
  i -= 655360;
  if (i < 262144) { W3b[i] = f2bf(c3w[i]); return; }
  i -= 262144;
  if (i < 32256) {    // OWt[(r*9+k)*512 + c] = outw[r*4608 + c*9 + k]
    int c = i & 511, rk = i >> 9;
    int r = rk / 9, k = rk - 9 * r;
    OWt[i] = outw[r * 4608 + c * 9 + k];
  }
}

// ---- build X0 AND T = gelu(inorm1_l0(X0)) from f32 emb ----------------------
__global__ void k_xng(const int* x, const float* emb, const float* g,
                      const float* bb, unsigned short* X, unsigned short* T,
                      int n0) {
  int idx = blockIdx.x * 256 + threadIdx.x;   // nc*128 threads
  int c4 = idx & 127, nl = idx >> 7;
  int gn = n0 + nl, b = gn >> 11, w = gn & 2047;
  size_t rbase = (size_t)(12 + nl * 12) * 512 + (c4 << 2);
  const int* xb = x + (b << 11);
  float v[9][4], s1[4] = {0.f, 0.f, 0.f, 0.f};
  #pragma unroll
  for (int k = 0; k < 9; k++) {
    int t = w + k; if (t > 2047) t = 2047;
    float4 ev = *(const float4*)(emb + xb[t] * 512 + (c4 << 2));
    v[k][0] = ev.x; v[k][1] = ev.y; v[k][2] = ev.z; v[k][3] = ev.w;
    usv4 pk;
    #pragma unroll
    for (int j = 0; j < 4; j++) { pk[j] = f2bf(v[k][j]); s1[j] += v[k][j]; }
    *(usv4*)(X + rbase + k * 512) = pk;
  }
  float mn[4], rr[4], gg[4], bo[4];
  #pragma unroll
  for (int j = 0; j < 4; j++) {
    mn[j] = s1[j] * (1.0f / 9.0f);
    float q = 0.f;
    #pragma unroll
    for (int k = 0; k < 9; k++) { float d = v[k][j] - mn[j]; q += d * d; }
    rr[j] = rsqrtf(q * (1.0f / 9.0f) + 1e-5f);
    gg[j] = g[(c4 << 2) + j]; bo[j] = bb[(c4 << 2) + j];
  }
  #pragma unroll
  for (int k = 0; k < 9; k++) {
    usv4 pk;
    #pragma unroll
    for (int j = 0; j < 4; j++)
      pk[j] = f2bf(gelu_(gg[j] * (v[k][j] - mn[j]) * rr[j] + bo[j]));
    *(usv4*)(T + rbase + k * 512) = pk;
  }
}

// ---- zero leading 12 pad rows of AL (conv tap shifts read rows 10-11) -------
__global__ void k_zpad(unsigned short* AL) {
  int i = threadIdx.x;
  for (; i < 12 * 256; i += 256) AL[i] = 0;
}

// ---- GEMM (MODE 0/1): tile 256(M) x 288(N=32 win), BK=64, 8 waves, dbuf ------
// MODE 0: A=W1b[256][512]  B=T (plain)              epi: inorm2+gelu->AL (+pad0)
// MODE 1: A=W2t[5][256][256] B=AL (tap rows, kb-major) epi: inorm3+gelu->AL2
template <int MODE>
__global__ __launch_bounds__(512, 2) void k_gemm(
    const unsigned short* __restrict__ Aw, const unsigned short* __restrict__ Bsrc,
    const float* __restrict__ gw, const float* __restrict__ gb,
    unsigned short* __restrict__ Out, int nkc) {
  // [A0 32K][A1 32K][B0 36K][B1 36K] bytes = 136 KB; epilogue sE reuses front
  __shared__ __align__(16) unsigned short smem[69632];
  unsigned short* sE = smem;                  // [288 col][CHP ch]

  const int KROW = (MODE == 0) ? 512 : 256;
  const int KSTEPS = (MODE == 1) ? 20 : 8;
  int tid = threadIdx.x, wv = tid >> 6, ln = tid & 63;
  int lr = ln >> 3, lu = ln & 7;
  int swz = (lu ^ lr) << 3;                   // staging src swizzle (elems)
  int w0 = blockIdx.x << 5;                   // first window of block
  int col0 = blockIdx.x * 288;

  int brow[5];
  #pragma unroll
  for (int s = 0; s < 5; s++) {
    int colg = col0 + (s << 6) + (wv << 3) + lr;
    if (colg >= nkc) colg = nkc - 1;
    brow[s] = colg + 3 * div9(colg) + 12;
  }

  f32x4 acc[4][9];
  #pragma unroll
  for (int i = 0; i < 4; i++)
    #pragma unroll
    for (int j = 0; j < 9; j++) acc[i][j] = (f32x4){0.f, 0.f, 0.f, 0.f};

  auto stage = [&](int buf, int ks) {
    int kb, dlt; const unsigned short* Ab;
    if (MODE == 1) {   // kb-major, tap-minor: 5 consecutive steps share B rows
      int t = ks % 5; kb = (ks / 5) << 6; dlt = t - 2; Ab = Aw + t * 65536;
    } else { kb = ks << 6; dlt = 0; Ab = Aw; }
    unsigned short* cA = smem + buf * 16384;
    unsigned short* cB = smem + 32768 + buf * 18432;
    #pragma unroll
    for (int p = 0; p < 4; p++) {
      int m = (p << 6) + (wv << 3) + lr;
      gload16(Ab + (size_t)m * KROW + kb + swz, cA + (p << 12) + (wv << 9));
    }
    #pragma unroll
    for (int s = 0; s < 4; s++)
      gload16(Bsrc + (size_t)(brow[s] + dlt) * KROW + kb + swz,
              cB + (s << 12) + (wv << 9));
    if (wv < 4)
      gload16(Bsrc + (size_t)(brow[4] + dlt) * KROW + kb + swz,
              cB + (4 << 12) + (wv << 9));
  };

  stage(0, 0);
  __syncthreads();

  int cur = 0;
  for (int ks = 0; ks < KSTEPS; ks++) {
    unsigned short* cA = smem + cur * 16384;
    unsigned short* cB = smem + 32768 + cur * 18432;

    if (ks + 1 < KSTEPS) stage(cur ^ 1, ks + 1);   // overlap with MFMA below

    int l16 = ln & 15, loct = ln >> 4;
    int wm = wv >> 1, wn = wv & 1;
    #pragma unroll
    for (int kk = 0; kk < 2; kk++) {
      int kbyte = (kk << 6) + (loct << 4);
      bfv8 af[4], bf_[9];
      #pragma unroll
      for (int mi = 0; mi < 4; mi++) {
        int row = (wm << 6) + (mi << 4) + l16;
        af[mi] = *(const bfv8*)((const char*)cA + row * 128 + (kbyte ^ ((row & 7) << 4)));
      }
      #pragma unroll
      for (int ni = 0; ni < 9; ni++) {
        int row = wn * 144 + (ni << 4) + l16;
        bf_[ni] = *(const bfv8*)((const char*)cB + row * 128 + (kbyte ^ ((row & 7) << 4)));
      }
      #pragma unroll
      for (int mi = 0; mi < 4; mi++)
        #pragma unroll
        for (int ni = 0; ni < 9; ni++)
          acc[mi][ni] = __builtin_amdgcn_mfma_f32_16x16x32_bf16(
              af[mi], bf_[ni], acc[mi][ni], 0, 0, 0);
    }
    __syncthreads();
    cur ^= 1;
  }

  // ---- fused epilogue: 2 rounds of 128 channels, col-major sE ----------------
  int l16 = ln & 15, loct = ln >> 4;
  #pragma unroll
  for (int R = 0; R < 2; R++) {
    if (R) __syncthreads();
    if ((wv >> 2) == R) {
      int chh = (((wv >> 1) & 1) << 6) + (loct << 2);
      int colb = (wv & 1) * 144 + l16;
      #pragma unroll
      for (int mi = 0; mi < 4; mi++) {
        #pragma unroll
        for (int ni = 0; ni < 9; ni++) {
          usv4 pk;
          #pragma unroll
          for (int q = 0; q < 4; q++) pk[q] = f2bf(acc[mi][ni][q]);
          *(usv4*)(sE + (colb + (ni << 4)) * CHP + chh + (mi << 4)) = pk;
        }
      }
    }
    __syncthreads();
    #pragma unroll
    for (int tt = 0; tt < 2; tt++) {
      int t = tid + tt * 512;                 // 1024 tasks: 32 chgrp x 32 win
      int c4 = t & 31, win = t >> 5;
      int chl = (R << 7) + (c4 << 2);
      const unsigned short* sb = sE + (win * 9) * CHP + (c4 << 2);
      size_t ob = (size_t)(12 + (size_t)(w0 + win) * 12) * 256 + chl;
      float s1[4] = {0.f, 0.f, 0.f, 0.f}, s2[4] = {0.f, 0.f, 0.f, 0.f};
      #pragma unroll
      for (int k = 0; k < 9; k++) {
        usv4 rv = *(const usv4*)(sb + k * CHP);
        #pragma unroll
        for (int j = 0; j < 4; j++) {
          float f = bf2f(rv[j]);
          s1[j] += f; s2[j] = __builtin_fmaf(f, f, s2[j]);
        }
      }
      float mn[4], rr[4], gg[4], bo[4];
      #pragma unroll
      for (int j = 0; j < 4; j++) {
        mn[j] = s1[j] * (1.0f / 9.0f);
        float var = s2[j] * (1.0f / 9.0f) - mn[j] * mn[j];
        rr[j] = rsqrtf(var + 1e-5f);
        gg[j] = gw[chl + j]; bo[j] = gb[chl + j];
      }
      #pragma unroll
      for (int k = 0; k < 9; k++) {
        usv4 rv = *(const usv4*)(sb + k * CHP);
        usv4 pk;
        #pragma unroll
        for (int j = 0; j < 4; j++)
          pk[j] = f2bf(gelu_(gg[j] * (bf2f(rv[j]) - mn[j]) * rr[j] + bo[j]));
        *(usv4*)(Out + ob + k * 256) = pk;
      }
      if (MODE == 0) {   // zero window pad rows for conv tap shifts
        usv4 z = (usv4){0, 0, 0, 0};
        *(usv4*)(Out + ob + 9 * 256) = z;
        *(usv4*)(Out + ob + 10 * 256) = z;
        *(usv4*)(Out + ob + 11 * 256) = z;
      }
    }
  }
}

// ---- GEMM c3: tile 128(M) x 144(N=16 win), BK=64, 4 waves, dbuf --------------
// 1-D grid, XCD-aware slab decode (R17). WT: epilogue also writes
// T = gelu(inorm1_next(newX)) for the next layer's MODE0.
template <bool WT>
__global__ __launch_bounds__(256, 2) void k_gemm2(
    const unsigned short* __restrict__ Aw, const unsigned short* __restrict__ Bsrc,
    const float* __restrict__ cbias, const float* __restrict__ n1w,
    const float* __restrict__ n1b, unsigned short* __restrict__ Out,
    unsigned short* __restrict__ Tout, int nkc) {
  __shared__ __align__(16) unsigned short smem[34816];
  unsigned short* sE = smem;

  const int KROW = 256, KSTEPS = 4;
  int tid = threadIdx.x, wv = tid >> 6, ln = tid & 63;
  int lr = ln >> 3, lu = ln & 7;
  int swz = (lu ^ lr) << 3;
  int id = blockIdx.x;
  int slab = (id >> 3) & 3;                   // M-slab 0..3
  int tile = ((id >> 5) << 3) | (id & 7);     // col-tile (tiles % 8 == 0)
  int m0 = slab << 7;
  int w0 = tile << 4;
  int col0 = tile * 144;

  int brow[5];
  #pragma unroll
  for (int s = 0; s < 5; s++) {
    int cl = (s < 4) ? ((s << 5) + (wv << 3) + lr) : (128 + (wv << 3) + lr);
    int colg = col0 + cl;
    if (colg >= nkc) colg = nkc - 1;
    brow[s] = colg + 3 * div9(colg) + 12;
  }
  const unsigned short* A0 = Aw + (size_t)m0 * KROW;

  f32x4 acc[2][9];
  #pragma unroll
  for (int i = 0; i < 2; i++)
    #pragma unroll
    for (int j = 0; j < 9; j++) acc[i][j] = (f32x4){0.f, 0.f, 0.f, 0.f};

  auto stage = [&](int buf, int ks) {
    int kb = ks << 6;
    unsigned short* cA = smem + buf * 8192;
    unsigned short* cB = smem + 16384 + buf * 9216;
    #pragma unroll
    for (int p = 0; p < 4; p++) {
      int m = (p << 5) + (wv << 3) + lr;
      gload16(A0 + (size_t)m * KROW + kb + swz, cA + ((p << 5) + (wv << 3)) * 64);
    }
    #pragma unroll
    for (int s = 0; s < 4; s++)
      gload16(Bsrc + (size_t)brow[s] * KROW + kb + swz,
              cB + ((s << 5) + (wv << 3)) * 64);
    if (wv < 2)
      gload16(Bsrc + (size_t)brow[4] * KROW + kb + swz,
              cB + (128 + (wv << 3)) * 64);
  };

  stage(0, 0);
  __syncthreads();

  int cur = 0;
  for (int ks = 0; ks < KSTEPS; ks++) {
    unsigned short* cA = smem + cur * 8192;
    unsigned short* cB = smem + 16384 + cur * 9216;
    if (ks + 1 < KSTEPS) stage(cur ^ 1, ks + 1);

    int l16 = ln & 15, loct = ln >> 4;
    #pragma unroll
    for (int kk = 0; kk < 2; kk++) {
      int kbyte = (kk << 6) + (loct << 4);
      bfv8 af[2], bf_[9];
      #pragma unroll
      for (int mi = 0; mi < 2; mi++) {
        int row = (wv << 5) + (mi << 4) + l16;
        af[mi] = *(const bfv8*)((const char*)cA + row * 128 + (kbyte ^ ((row & 7) << 4)));
      }
      #pragma unroll
      for (int ni = 0; ni < 9; ni++) {
        int row = (ni << 4) + l16;
        bf_[ni] = *(const bfv8*)((const char*)cB + row * 128 + (kbyte ^ ((row & 7) << 4)));
      }
      #pragma unroll
      for (int mi = 0; mi < 2; mi++)
        #pragma unroll
        for (int ni = 0; ni < 9; ni++)
          acc[mi][ni] = __builtin_amdgcn_mfma_f32_16x16x32_bf16(
              af[mi], bf_[ni], acc[mi][ni], 0, 0, 0);
    }
    __syncthreads();
    cur ^= 1;
  }

  // ---- epilogue: bias + residual -> X; WT: also T = gelu(inorm1(newX)) ------
  int l16 = ln & 15, loct = ln >> 4;
  int c4 = tid & 15, win = tid >> 4;
  #pragma unroll
  for (int R = 0; R < 2; R++) {
    if (R) __syncthreads();
    if ((wv >> 1) == R) {
      int chh = ((wv & 1) << 5) + (loct << 2);
      #pragma unroll
      for (int mi = 0; mi < 2; mi++) {
        #pragma unroll
        for (int ni = 0; ni < 9; ni++) {
          usv4 pk;
          #pragma unroll
          for (int q = 0; q < 4; q++) pk[q] = f2bf(acc[mi][ni][q]);
          *(usv4*)(sE + ((ni << 4) + l16) * CHP2 + chh + (mi << 4)) = pk;
        }
      }
    }
    __syncthreads();
    {
      int chg = m0 + (R << 6) + (c4 << 2);
      const unsigned short* sb = sE + (win * 9) * CHP2 + (c4 << 2);
      size_t ob = (size_t)(12 + (size_t)(w0 + win) * 12) * 512 + chg;
      float cb[4];
      #pragma unroll
      for (int j = 0; j < 4; j++) cb[j] = cbias[chg + j];
      float v[9][4], s1[4] = {0.f, 0.f, 0.f, 0.f};
      #pragma unroll
      for (int k = 0; k < 9; k++) {
        usv4 rv = *(const usv4*)(sb + k * CHP2);
        usv4 old = *(usv4*)(Out + ob + k * 512);
        usv4 pk;
        #pragma unroll
        for (int j = 0; j < 4; j++) {
          float f = bf2f(rv[j]) + cb[j] + bf2f(old[j]);
          v[k][j] = f; s1[j] += f;
          pk[j] = f2bf(f);
        }
        *(usv4*)(Out + ob + k * 512) = pk;
      }
      if (WT) {
        float mn[4], rr[4], gg[4], bo[4];
        #pragma unroll
        for (int j = 0; j < 4; j++) {
          mn[j] = s1[j] * (1.0f / 9.0f);
          float q = 0.f;
          #pragma unroll
          for (int k = 0; k < 9; k++) { float d = v[k][j] - mn[j]; q += d * d; }
          rr[j] = rsqrtf(q * (1.0f / 9.0f) + 1e-5f);
          gg[j] = n1w[chg + j]; bo[j] = n1b[chg + j];
        }
        #pragma unroll
        for (int k = 0; k < 9; k++) {
          usv4 pk;
          #pragma unroll
          for (int j = 0; j < 4; j++)
            pk[j] = f2bf(gelu_(gg[j] * (v[k][j] - mn[j]) * rr[j] + bo[j]));
          *(usv4*)(Tout + ob + k * 512) = pk;
        }
      }
    }
  }
}

// ---- output projection: one wave per window, fp32 weights -------------------
__global__ void k_out(const unsigned short* X, const float* OWt, const float* outb,
                      float* pred, int n0, int nc) {
  int gw = (blockIdx.x * 256 + threadIdx.x) >> 6;
  int ln = threadIdx.x & 63;
  if (gw >= nc) return;
  int gn = n0 + gw, b = gn >> 11, w = gn & 2047;
  if (w >= 2040) return;
  const unsigned short* xb = X + (size_t)(12 + gw * 12) * 512 + ln * 8;
  float a[7];
  #pragma unroll
  for (int r = 0; r < 7; r++) a[r] = 0.f;
  for (int k = 0; k < 9; k++) {
    bfv8 xv = *(const bfv8*)(xb + k * 512);
    float xf[8];
    #pragma unroll
    for (int j = 0; j < 8; j++) xf[j] = bf2f((unsigned short)xv[j]);
    #pragma unroll
    for (int r = 0; r < 7; r++) {
      const float* wp = OWt + (r * 9 + k) * 512 + ln * 8;
      float4 w0 = *(const float4*)(wp);
      float4 w1 = *(const float4*)(wp + 4);
      a[r] += xf[0] * w0.x + xf[1] * w0.y + xf[2] * w0.z + xf[3] * w0.w +
              xf[4] * w1.x + xf[5] * w1.y + xf[6] * w1.z + xf[7] * w1.w;
    }
  }
  #pragma unroll
  for (int r = 0; r < 7; r++)
    for (int off = 32; off; off >>= 1) a[r] += __shfl_down(a[r], off);
  if (ln == 0) {
    float* o = pred + (size_t)(b * 2040 + w) * 7;
    #pragma unroll
    for (int r = 0; r < 7; r++) o[r] = a[r] + outb[r];
  }
}

extern "C" void kernel_launch(void* const* d_in, const int* in_sizes, int n_in,
                              void* d_out, int out_size, void* d_ws, size_t ws_size,
                              hipStream_t stream) {
  const int*   x    = (const int*)d_in[0];
  const float* emb  = (const float*)d_in[1];
  const float* ln1w = (const float*)d_in[2];
  const float* ln1b = (const float*)d_in[3];
  const float* ln2w = (const float*)d_in[4];
  const float* ln2b = (const float*)d_in[5];
  const float* ln3w = (const float*)d_in[6];
  const float* ln3b = (const float*)d_in[7];
  const float* c1w  = (const float*)d_in[8];
  const float* c2w  = (const float*)d_in[10];
  const float* c3w  = (const float*)d_in[12];
  const float* c3b  = (const float*)d_in[13];
  const float* outw = (const float*)d_in[14];
  const float* outb = (const float*)d_in[15];
  float* pred = (float*)d_out;

  // footprint = weights 2488320 + (nc+1)*12*2*(512 X + 512 T + 256 + 256)
  int nc = 8192;
  while (nc > 128 &&
         2488320ull + (unsigned long long)(nc + 1) * 36864ull > ws_size)
    nc >>= 1;
  int nkc = nc * 9;
  int tiles288 = nc >> 5;
  int tiles144 = nc >> 4;
  int nchunks = 16384 / nc;

  char* ws = (char*)d_ws;
  unsigned short* W1b = (unsigned short*)(ws);
  unsigned short* W2t = (unsigned short*)(ws + 524288);
  unsigned short* W3b = (unsigned short*)(ws + 1835008);
  float*          OWt = (float*)(ws + 2359296);
  char* act = ws + 2488320;
  size_t hiB = (size_t)(nc + 1) * 12288;
  size_t loB = (size_t)(nc + 1) * 6144;
  unsigned short* X   = (unsigned short*)(act);
  unsigned short* T   = (unsigned short*)(act + hiB);
  unsigned short* AL  = (unsigned short*)(act + 2 * hiB);
  unsigned short* AL2 = (unsigned short*)(act + 2 * hiB + loB);

  k_prep<<<(1211904 + 255) / 256, 256, 0, stream>>>(c1w, c2w, c3w, outw,
                                                    W1b, W2t, W3b, OWt);
  k_zpad<<<1, 256, 0, stream>>>(AL);

  for (int ch = 0; ch < nchunks; ch++) {
    int n0 = ch * nc;
    k_xng<<<nc / 2, 256, 0, stream>>>(x, emb, ln1w, ln1b, X, T, n0);
    for (int l = 0; l < 2; l++) {
      k_gemm<0><<<dim3(tiles288, 1), 512, 0, stream>>>(
          W1b + l * 131072, T, ln2w + l * 256, ln2b + l * 256, AL, nkc);
      k_gemm<1><<<dim3(tiles288, 1), 512, 0, stream>>>(
          W2t + l * 327680, AL, ln3w + l * 256, ln3b + l * 256, AL2, nkc);
      if (l == 0)
        k_gemm2<true><<<tiles144 * 4, 256, 0, stream>>>(
            W3b, AL2, c3b, ln1w + 512, ln1b + 512, X, T, nkc);
      else
        k_gemm2<false><<<tiles144 * 4, 256, 0, stream>>>(
            W3b + 131072, AL2, c3b + 512, nullptr, nullptr, X, nullptr, nkc);
    }
    k_out<<<nc / 4, 256, 0, stream>>>(X, OWt, outb, pred, n0, nc);
  }
}

// Round 19
// 808.593 us; speedup vs baseline: 1.2919x; 1.2919x over previous
//
#include <hip/hip_runtime.h>

typedef __attribute__((ext_vector_type(8))) short bfv8;
typedef __attribute__((ext_vector_type(4))) float f32x4;
typedef __attribute__((ext_vector_type(4))) unsigned short usv4;

typedef __attribute__((address_space(1))) const void gvoid;
typedef __attribute__((address_space(3))) void lvoid;
__device__ __forceinline__ void gload16(const void* g, void* l) {
  __builtin_amdgcn_global_load_lds((gvoid*)g, (lvoid*)l, 16, 0, 0);
}

__device__ __forceinline__ float bf2f(unsigned short u) {
  union { unsigned int i; float f; } c; c.i = ((unsigned int)u) << 16; return c.f;
}
__device__ __forceinline__ unsigned short f2bf(float f) {
  union { float f; unsigned int i; } c; c.f = f;
  unsigned int r = c.i + 0x7FFFu + ((c.i >> 16) & 1u);
  return (unsigned short)(r >> 16);
}
// tanh-form gelu via hw exp+rcp (max dev from erf-gelu ~5e-4)
__device__ __forceinline__ float gelu_(float x) {
  float z2 = 1.5957691216057308f * x * __builtin_fmaf(0.044715f, x * x, 1.0f);
  float e = __expf(z2);
  float t = __builtin_amdgcn_rcpf(e + 1.0f);
  return x - x * t;
}
__device__ __forceinline__ int div9(int col) {
  return (int)(__umulhi((unsigned)col, 954437177u) >> 1);
}

#define CHP 132   // big-kernel epilogue LDS channel stride (u16)
#define CHP2 66   // gemm2 kernel epilogue stride

// ---- weight prep ------------------------------------------------------------
__global__ void k_prep(const float* c1w, const float* c2w, const float* c3w,
                       const float* outw, unsigned short* W1b, unsigned short* W2t,
                       unsigned short* W3b, float* OWt) {
  int i = blockIdx.x * 256 + threadIdx.x;
  if (i < 262144) { W1b[i] = f2bf(c1w[i]); return; }
  i -= 262144;
  if (i < 655360) {   // W2t[l][t][o][ii] = c2w[l][o][ii][t]
    int ii = i & 255, o = (i >> 8) & 255, rest = i >> 16;
    int t = rest % 5, l = rest / 5;
    W2t[i] = f2bf(c2w[(((l * 256 + o) << 8) + ii) * 5 + t]);
    return;
  }
  i -= 655360;
  if (i < 262144) { W3b[i] = f2bf(c3w[i]); return; }
  i -= 262144;
  if (i < 32256) {    // OWt[(r*9+k)*512 + c] = outw[r*4608 + c*9 + k]
    int c = i & 511, rk = i >> 9;
    int r = rk / 9, k = rk - 9 * r;
    OWt[i] = outw[r * 4608 + c * 9 + k];
  }
}

// ---- build X0 AND T = gelu(inorm1_l0(X0)); X/T unpadded [n*9+k][512] --------
__global__ void k_xng(const int* x, const float* emb, const float* g,
                      const float* bb, unsigned short* X, unsigned short* T,
                      int n0) {
  int idx = blockIdx.x * 256 + threadIdx.x;   // nc*128 threads
  int c4 = idx & 127, nl = idx >> 7;
  int gn = n0 + nl, b = gn >> 11, w = gn & 2047;
  size_t rbase = (size_t)nl * 9 * 512 + (c4 << 2);
  const int* xb = x + (b << 11);
  float v[9][4], s1[4] = {0.f, 0.f, 0.f, 0.f};
  #pragma unroll
  for (int k = 0; k < 9; k++) {
    int t = w + k; if (t > 2047) t = 2047;
    float4 ev = *(const float4*)(emb + xb[t] * 512 + (c4 << 2));
    v[k][0] = ev.x; v[k][1] = ev.y; v[k][2] = ev.z; v[k][3] = ev.w;
    usv4 pk;
    #pragma unroll
    for (int j = 0; j < 4; j++) { pk[j] = f2bf(v[k][j]); s1[j] += v[k][j]; }
    *(usv4*)(X + rbase + k * 512) = pk;
  }
  float mn[4], rr[4], gg[4], bo[4];
  #pragma unroll
  for (int j = 0; j < 4; j++) {
    mn[j] = s1[j] * (1.0f / 9.0f);
    float q = 0.f;
    #pragma unroll
    for (int k = 0; k < 9; k++) { float d = v[k][j] - mn[j]; q += d * d; }
    rr[j] = rsqrtf(q * (1.0f / 9.0f) + 1e-5f);
    gg[j] = g[(c4 << 2) + j]; bo[j] = bb[(c4 << 2) + j];
  }
  #pragma unroll
  for (int k = 0; k < 9; k++) {
    usv4 pk;
    #pragma unroll
    for (int j = 0; j < 4; j++)
      pk[j] = f2bf(gelu_(gg[j] * (v[k][j] - mn[j]) * rr[j] + bo[j]));
    *(usv4*)(T + rbase + k * 512) = pk;
  }
}

// ---- zero leading 12 pad rows of AL (conv tap shifts read rows 10-11) -------
__global__ void k_zpad(unsigned short* AL) {
  int i = threadIdx.x;
  for (; i < 12 * 256; i += 256) AL[i] = 0;
}

// ---- GEMM (MODE 0/1): tile 256(M) x 288(N=32 win), BK=64, 8 waves, dbuf ------
// MODE 0: A=W1b[256][512]  B=T (unpadded, row=col)  epi: inorm2+gelu->AL(+pad0)
// MODE 1: A=W2t[5][256][256] B=AL padded (tap rows) epi: inorm3+gelu->AL2 unpad
template <int MODE>
__global__ __launch_bounds__(512, 2) void k_gemm(
    const unsigned short* __restrict__ Aw, const unsigned short* __restrict__ Bsrc,
    const float* __restrict__ gw, const float* __restrict__ gb,
    unsigned short* __restrict__ Out, int nkc) {
  // [A0 32K][A1 32K][B0 36K][B1 36K] bytes = 136 KB; epilogue sE reuses front
  __shared__ __align__(16) unsigned short smem[69632];
  unsigned short* sE = smem;                  // [288 col][CHP ch]

  const int KROW = (MODE == 0) ? 512 : 256;
  const int KSTEPS = (MODE == 1) ? 20 : 8;
  int tid = threadIdx.x, wv = tid >> 6, ln = tid & 63;
  int lr = ln >> 3, lu = ln & 7;
  int swz = (lu ^ lr) << 3;                   // staging src swizzle (elems)
  int w0 = blockIdx.x << 5;                   // first window of block
  int col0 = blockIdx.x * 288;

  int brow[5];
  #pragma unroll
  for (int s = 0; s < 5; s++) {
    int colg = col0 + (s << 6) + (wv << 3) + lr;
    if (colg >= nkc) colg = nkc - 1;
    brow[s] = (MODE == 0) ? colg : (colg + 3 * div9(colg) + 12);
  }

  f32x4 acc[4][9];
  #pragma unroll
  for (int i = 0; i < 4; i++)
    #pragma unroll
    for (int j = 0; j < 9; j++) acc[i][j] = (f32x4){0.f, 0.f, 0.f, 0.f};

  auto stage = [&](int buf, int ks) {
    int kb, dlt; const unsigned short* Ab;
    if (MODE == 1) {   // kb-major, tap-minor: 5 consecutive steps share B rows
      int t = ks % 5; kb = (ks / 5) << 6; dlt = t - 2; Ab = Aw + t * 65536;
    } else { kb = ks << 6; dlt = 0; Ab = Aw; }
    unsigned short* cA = smem + buf * 16384;
    unsigned short* cB = smem + 32768 + buf * 18432;
    #pragma unroll
    for (int p = 0; p < 4; p++) {
      int m = (p << 6) + (wv << 3) + lr;
      gload16(Ab + (size_t)m * KROW + kb + swz, cA + (p << 12) + (wv << 9));
    }
    #pragma unroll
    for (int s = 0; s < 4; s++)
      gload16(Bsrc + (size_t)(brow[s] + dlt) * KROW + kb + swz,
              cB + (s << 12) + (wv << 9));
    if (wv < 4)
      gload16(Bsrc + (size_t)(brow[4] + dlt) * KROW + kb + swz,
              cB + (4 << 12) + (wv << 9));
  };

  stage(0, 0);
  __syncthreads();

  int cur = 0;
  for (int ks = 0; ks < KSTEPS; ks++) {
    unsigned short* cA = smem + cur * 16384;
    unsigned short* cB = smem + 32768 + cur * 18432;

    if (ks + 1 < KSTEPS) stage(cur ^ 1, ks + 1);   // overlap with MFMA below

    int l16 = ln & 15, loct = ln >> 4;
    int wm = wv >> 1, wn = wv & 1;
    #pragma unroll
    for (int kk = 0; kk < 2; kk++) {
      int kbyte = (kk << 6) + (loct << 4);
      bfv8 af[4], bf_[9];
      #pragma unroll
      for (int mi = 0; mi < 4; mi++) {
        int row = (wm << 6) + (mi << 4) + l16;
        af[mi] = *(const bfv8*)((const char*)cA + row * 128 + (kbyte ^ ((row & 7) << 4)));
      }
      #pragma unroll
      for (int ni = 0; ni < 9; ni++) {
        int row = wn * 144 + (ni << 4) + l16;
        bf_[ni] = *(const bfv8*)((const char*)cB + row * 128 + (kbyte ^ ((row & 7) << 4)));
      }
      #pragma unroll
      for (int mi = 0; mi < 4; mi++)
        #pragma unroll
        for (int ni = 0; ni < 9; ni++)
          acc[mi][ni] = __builtin_amdgcn_mfma_f32_16x16x32_bf16(
              af[mi], bf_[ni], acc[mi][ni], 0, 0, 0);
    }
    __syncthreads();
    cur ^= 1;
  }

  // ---- fused epilogue: 2 rounds of 128 channels, col-major sE ----------------
  int l16 = ln & 15, loct = ln >> 4;
  #pragma unroll
  for (int R = 0; R < 2; R++) {
    if (R) __syncthreads();
    if ((wv >> 2) == R) {
      int chh = (((wv >> 1) & 1) << 6) + (loct << 2);
      int colb = (wv & 1) * 144 + l16;
      #pragma unroll
      for (int mi = 0; mi < 4; mi++) {
        #pragma unroll
        for (int ni = 0; ni < 9; ni++) {
          usv4 pk;
          #pragma unroll
          for (int q = 0; q < 4; q++) pk[q] = f2bf(acc[mi][ni][q]);
          *(usv4*)(sE + (colb + (ni << 4)) * CHP + chh + (mi << 4)) = pk;
        }
      }
    }
    __syncthreads();
    #pragma unroll
    for (int tt = 0; tt < 2; tt++) {
      int t = tid + tt * 512;                 // 1024 tasks: 32 chgrp x 32 win
      int c4 = t & 31, win = t >> 5;
      int chl = (R << 7) + (c4 << 2);
      const unsigned short* sb = sE + (win * 9) * CHP + (c4 << 2);
      size_t ob;
      if (MODE == 0)       // AL padded layout
        ob = (size_t)(12 + (size_t)(w0 + win) * 12) * 256 + chl;
      else                 // AL2 unpadded
        ob = (size_t)(w0 + win) * 9 * 256 + chl;
      float s1[4] = {0.f, 0.f, 0.f, 0.f}, s2[4] = {0.f, 0.f, 0.f, 0.f};
      #pragma unroll
      for (int k = 0; k < 9; k++) {
        usv4 rv = *(const usv4*)(sb + k * CHP);
        #pragma unroll
        for (int j = 0; j < 4; j++) {
          float f = bf2f(rv[j]);
          s1[j] += f; s2[j] = __builtin_fmaf(f, f, s2[j]);
        }
      }
      float mn[4], rr[4], gg[4], bo[4];
      #pragma unroll
      for (int j = 0; j < 4; j++) {
        mn[j] = s1[j] * (1.0f / 9.0f);
        float var = s2[j] * (1.0f / 9.0f) - mn[j] * mn[j];
        rr[j] = rsqrtf(var + 1e-5f);
        gg[j] = gw[chl + j]; bo[j] = gb[chl + j];
      }
      #pragma unroll
      for (int k = 0; k < 9; k++) {
        usv4 rv = *(const usv4*)(sb + k * CHP);
        usv4 pk;
        #pragma unroll
        for (int j = 0; j < 4; j++)
          pk[j] = f2bf(gelu_(gg[j] * (bf2f(rv[j]) - mn[j]) * rr[j] + bo[j]));
        *(usv4*)(Out + ob + k * 256) = pk;
      }
      if (MODE == 0) {   // zero window pad rows for conv tap shifts
        usv4 z = (usv4){0, 0, 0, 0};
        *(usv4*)(Out + ob + 9 * 256) = z;
        *(usv4*)(Out + ob + 10 * 256) = z;
        *(usv4*)(Out + ob + 11 * 256) = z;
      }
    }
  }
}

// ---- GEMM c3: tile 128(M) x 144(N=16 win), BK=64, 4 waves, dbuf --------------
// 1-D grid, XCD-aware slab decode (R17). B=AL2 unpadded (row=col).
// WT: epilogue also writes T = gelu(inorm1_next(newX)).
template <bool WT>
__global__ __launch_bounds__(256, 2) void k_gemm2(
    const unsigned short* __restrict__ Aw, const unsigned short* __restrict__ Bsrc,
    const float* __restrict__ cbias, const float* __restrict__ n1w,
    const float* __restrict__ n1b, unsigned short* __restrict__ Out,
    unsigned short* __restrict__ Tout, int nkc) {
  __shared__ __align__(16) unsigned short smem[34816];
  unsigned short* sE = smem;

  const int KROW = 256, KSTEPS = 4;
  int tid = threadIdx.x, wv = tid >> 6, ln = tid & 63;
  int lr = ln >> 3, lu = ln & 7;
  int swz = (lu ^ lr) << 3;
  int id = blockIdx.x;
  int slab = (id >> 3) & 3;                   // M-slab 0..3
  int tile = ((id >> 5) << 3) | (id & 7);     // col-tile (tiles % 8 == 0)
  int m0 = slab << 7;
  int w0 = tile << 4;
  int col0 = tile * 144;

  int brow[5];
  #pragma unroll
  for (int s = 0; s < 5; s++) {
    int cl = (s < 4) ? ((s << 5) + (wv << 3) + lr) : (128 + (wv << 3) + lr);
    int colg = col0 + cl;
    if (colg >= nkc) colg = nkc - 1;
    brow[s] = colg;                           // AL2 unpadded
  }
  const unsigned short* A0 = Aw + (size_t)m0 * KROW;

  f32x4 acc[2][9];
  #pragma unroll
  for (int i = 0; i < 2; i++)
    #pragma unroll
    for (int j = 0; j < 9; j++) acc[i][j] = (f32x4){0.f, 0.f, 0.f, 0.f};

  auto stage = [&](int buf, int ks) {
    int kb = ks << 6;
    unsigned short* cA = smem + buf * 8192;
    unsigned short* cB = smem + 16384 + buf * 9216;
    #pragma unroll
    for (int p = 0; p < 4; p++) {
      int m = (p << 5) + (wv << 3) + lr;
      gload16(A0 + (size_t)m * KROW + kb + swz, cA + ((p << 5) + (wv << 3)) * 64);
    }
    #pragma unroll
    for (int s = 0; s < 4; s++)
      gload16(Bsrc + (size_t)brow[s] * KROW + kb + swz,
              cB + ((s << 5) + (wv << 3)) * 64);
    if (wv < 2)
      gload16(Bsrc + (size_t)brow[4] * KROW + kb + swz,
              cB + (128 + (wv << 3)) * 64);
  };

  stage(0, 0);
  __syncthreads();

  int cur = 0;
  for (int ks = 0; ks < KSTEPS; ks++) {
    unsigned short* cA = smem + cur * 8192;
    unsigned short* cB = smem + 16384 + cur * 9216;
    if (ks + 1 < KSTEPS) stage(cur ^ 1, ks + 1);

    int l16 = ln & 15, loct = ln >> 4;
    #pragma unroll
    for (int kk = 0; kk < 2; kk++) {
      int kbyte = (kk << 6) + (loct << 4);
      bfv8 af[2], bf_[9];
      #pragma unroll
      for (int mi = 0; mi < 2; mi++) {
        int row = (wv << 5) + (mi << 4) + l16;
        af[mi] = *(const bfv8*)((const char*)cA + row * 128 + (kbyte ^ ((row & 7) << 4)));
      }
      #pragma unroll
      for (int ni = 0; ni < 9; ni++) {
        int row = (ni << 4) + l16;
        bf_[ni] = *(const bfv8*)((const char*)cB + row * 128 + (kbyte ^ ((row & 7) << 4)));
      }
      #pragma unroll
      for (int mi = 0; mi < 2; mi++)
        #pragma unroll
        for (int ni = 0; ni < 9; ni++)
          acc[mi][ni] = __builtin_amdgcn_mfma_f32_16x16x32_bf16(
              af[mi], bf_[ni], acc[mi][ni], 0, 0, 0);
    }
    __syncthreads();
    cur ^= 1;
  }

  // ---- epilogue: bias + residual -> X (unpadded); WT: T = gelu(inorm1) ------
  int l16 = ln & 15, loct = ln >> 4;
  int c4 = tid & 15, win = tid >> 4;
  #pragma unroll
  for (int R = 0; R < 2; R++) {
    if (R) __syncthreads();
    if ((wv >> 1) == R) {
      int chh = ((wv & 1) << 5) + (loct << 2);
      #pragma unroll
      for (int mi = 0; mi < 2; mi++) {
        #pragma unroll
        for (int ni = 0; ni < 9; ni++) {
          usv4 pk;
          #pragma unroll
          for (int q = 0; q < 4; q++) pk[q] = f2bf(acc[mi][ni][q]);
          *(usv4*)(sE + ((ni << 4) + l16) * CHP2 + chh + (mi << 4)) = pk;
        }
      }
    }
    __syncthreads();
    {
      int chg = m0 + (R << 6) + (c4 << 2);
      const unsigned short* sb = sE + (win * 9) * CHP2 + (c4 << 2);
      size_t ob = (size_t)(w0 + win) * 9 * 512 + chg;
      float cb[4];
      #pragma unroll
      for (int j = 0; j < 4; j++) cb[j] = cbias[chg + j];
      float v[9][4], s1[4] = {0.f, 0.f, 0.f, 0.f};
      #pragma unroll
      for (int k = 0; k < 9; k++) {
        usv4 rv = *(const usv4*)(sb + k * CHP2);
        usv4 old = *(usv4*)(Out + ob + k * 512);
        usv4 pk;
        #pragma unroll
        for (int j = 0; j < 4; j++) {
          float f = bf2f(rv[j]) + cb[j] + bf2f(old[j]);
          v[k][j] = f; s1[j] += f;
          pk[j] = f2bf(f);
        }
        *(usv4*)(Out + ob + k * 512) = pk;
      }
      if (WT) {
        float mn[4], rr[4], gg[4], bo[4];
        #pragma unroll
        for (int j = 0; j < 4; j++) {
          mn[j] = s1[j] * (1.0f / 9.0f);
          float q = 0.f;
          #pragma unroll
          for (int k = 0; k < 9; k++) { float d = v[k][j] - mn[j]; q += d * d; }
          rr[j] = rsqrtf(q * (1.0f / 9.0f) + 1e-5f);
          gg[j] = n1w[chg + j]; bo[j] = n1b[chg + j];
        }
        #pragma unroll
        for (int k = 0; k < 9; k++) {
          usv4 pk;
          #pragma unroll
          for (int j = 0; j < 4; j++)
            pk[j] = f2bf(gelu_(gg[j] * (v[k][j] - mn[j]) * rr[j] + bo[j]));
          *(usv4*)(Tout + ob + k * 512) = pk;
        }
      }
    }
  }
}

// ---- output projection: one wave per window, fp32 weights -------------------
__global__ void k_out(const unsigned short* X, const float* OWt, const float* outb,
                      float* pred, int n0, int nc) {
  int gw = (blockIdx.x * 256 + threadIdx.x) >> 6;
  int ln = threadIdx.x & 63;
  if (gw >= nc) return;
  int gn = n0 + gw, b = gn >> 11, w = gn & 2047;
  if (w >= 2040) return;
  const unsigned short* xb = X + (size_t)gw * 9 * 512 + ln * 8;
  float a[7];
  #pragma unroll
  for (int r = 0; r < 7; r++) a[r] = 0.f;
  for (int k = 0; k < 9; k++) {
    bfv8 xv = *(const bfv8*)(xb + k * 512);
    float xf[8];
    #pragma unroll
    for (int j = 0; j < 8; j++) xf[j] = bf2f((unsigned short)xv[j]);
    #pragma unroll
    for (int r = 0; r < 7; r++) {
      const float* wp = OWt + (r * 9 + k) * 512 + ln * 8;
      float4 w0 = *(const float4*)(wp);
      float4 w1 = *(const float4*)(wp + 4);
      a[r] += xf[0] * w0.x + xf[1] * w0.y + xf[2] * w0.z + xf[3] * w0.w +
              xf[4] * w1.x + xf[5] * w1.y + xf[6] * w1.z + xf[7] * w1.w;
    }
  }
  #pragma unroll
  for (int r = 0; r < 7; r++)
    for (int off = 32; off; off >>= 1) a[r] += __shfl_down(a[r], off);
  if (ln == 0) {
    float* o = pred + (size_t)(b * 2040 + w) * 7;
    #pragma unroll
    for (int r = 0; r < 7; r++) o[r] = a[r] + outb[r];
  }
}

extern "C" void kernel_launch(void* const* d_in, const int* in_sizes, int n_in,
                              void* d_out, int out_size, void* d_ws, size_t ws_size,
                              hipStream_t stream) {
  const int*   x    = (const int*)d_in[0];
  const float* emb  = (const float*)d_in[1];
  const float* ln1w = (const float*)d_in[2];
  const float* ln1b = (const float*)d_in[3];
  const float* ln2w = (const float*)d_in[4];
  const float* ln2b = (const float*)d_in[5];
  const float* ln3w = (const float*)d_in[6];
  const float* ln3b = (const float*)d_in[7];
  const float* c1w  = (const float*)d_in[8];
  const float* c2w  = (const float*)d_in[10];
  const float* c3w  = (const float*)d_in[12];
  const float* c3b  = (const float*)d_in[13];
  const float* outw = (const float*)d_in[14];
  const float* outb = (const float*)d_in[15];
  float* pred = (float*)d_out;

  // per-window: X 9216 + T 9216 + AL 6144(12-row) + AL2 4608 = 29184 B
  int nc = 8192;
  while (nc > 128 &&
         2488320ull + (unsigned long long)(nc + 1) * 29184ull > ws_size)
    nc >>= 1;
  int nkc = nc * 9;
  int tiles288 = nc >> 5;
  int tiles144 = nc >> 4;
  int nchunks = 16384 / nc;

  char* ws = (char*)d_ws;
  unsigned short* W1b = (unsigned short*)(ws);
  unsigned short* W2t = (unsigned short*)(ws + 524288);
  unsigned short* W3b = (unsigned short*)(ws + 1835008);
  float*          OWt = (float*)(ws + 2359296);
  char* act = ws + 2488320;
  size_t xB  = (size_t)(nc + 1) * 9216;      // unpadded 9-row x 512ch
  size_t alB = (size_t)(nc + 1) * 6144;      // padded 12-row x 256ch
  unsigned short* X   = (unsigned short*)(act);
  unsigned short* T   = (unsigned short*)(act + xB);
  unsigned short* AL  = (unsigned short*)(act + 2 * xB);
  unsigned short* AL2 = (unsigned short*)(act + 2 * xB + alB);

  k_prep<<<(1211904 + 255) / 256, 256, 0, stream>>>(c1w, c2w, c3w, outw,
                                                    W1b, W2t, W3b, OWt);
  k_zpad<<<1, 256, 0, stream>>>(AL);

  for (int ch = 0; ch < nchunks; ch++) {
    int n0 = ch * nc;
    k_xng<<<nc / 2, 256, 0, stream>>>(x, emb, ln1w, ln1b, X, T, n0);
    for (int l = 0; l < 2; l++) {
      k_gemm<0><<<dim3(tiles288, 1), 512, 0, stream>>>(
          W1b + l * 131072, T, ln2w + l * 256, ln2b + l * 256, AL, nkc);
      k_gemm<1><<<dim3(tiles288, 1), 512, 0, stream>>>(
          W2t + l * 327680, AL, ln3w + l * 256, ln3b + l * 256, AL2, nkc);
      if (l == 0)
        k_gemm2<true><<<tiles144 * 4, 256, 0, stream>>>(
            W3b, AL2, c3b, ln1w + 512, ln1b + 512, X, T, nkc);
      else
        k_gemm2<false><<<tiles144 * 4, 256, 0, stream>>>(
            W3b + 131072, AL2, c3b + 512, nullptr, nullptr, X, nullptr, nkc);
    }
    k_out<<<nc / 4, 256, 0, stream>>>(X, OWt, outb, pred, n0, nc);
  }
}

// Round 20
// 757.413 us; speedup vs baseline: 1.3792x; 1.0676x over previous
//
#include <hip/hip_runtime.h>

typedef __attribute__((ext_vector_type(8))) short bfv8;
typedef __attribute__((ext_vector_type(4))) float f32x4;
typedef __attribute__((ext_vector_type(4))) unsigned short usv4;

typedef __attribute__((address_space(1))) const void gvoid;
typedef __attribute__((address_space(3))) void lvoid;
__device__ __forceinline__ void gload16(const void* g, void* l) {
  __builtin_amdgcn_global_load_lds((gvoid*)g, (lvoid*)l, 16, 0, 0);
}

__device__ __forceinline__ float bf2f(unsigned short u) {
  union { unsigned int i; float f; } c; c.i = ((unsigned int)u) << 16; return c.f;
}
__device__ __forceinline__ unsigned short f2bf(float f) {
  union { float f; unsigned int i; } c; c.f = f;
  unsigned int r = c.i + 0x7FFFu + ((c.i >> 16) & 1u);
  return (unsigned short)(r >> 16);
}
// tanh-form gelu via hw exp+rcp (max dev from erf-gelu ~5e-4)
__device__ __forceinline__ float gelu_(float x) {
  float z2 = 1.5957691216057308f * x * __builtin_fmaf(0.044715f, x * x, 1.0f);
  float e = __expf(z2);
  float t = __builtin_amdgcn_rcpf(e + 1.0f);
  return x - x * t;
}
__device__ __forceinline__ int div9(int col) {
  return (int)(__umulhi((unsigned)col, 954437177u) >> 1);
}

#define CHP 132   // big-kernel epilogue LDS channel stride (u16)
#define CHP2 66   // gemm2 kernel epilogue stride

// ---- weight prep ------------------------------------------------------------
__global__ void k_prep(const float* c1w, const float* c2w, const float* c3w,
                       const float* outw, unsigned short* W1b, unsigned short* W2t,
                       unsigned short* W3b, float* OWt) {
  int i = blockIdx.x * 256 + threadIdx.x;
  if (i < 262144) { W1b[i] = f2bf(c1w[i]); return; }
  i -= 262144;
  if (i < 655360) {   // W2t[l][t][o][ii] = c2w[l][o][ii][t]
    int ii = i & 255, o = (i >> 8) & 255, rest = i >> 16;
    int t = rest % 5, l = rest / 5;
    W2t[i] = f2bf(c2w[(((l * 256 + o) << 8) + ii) * 5 + t]);
    return;
  }
  i -= 655360;
  if (i < 262144) { W3b[i] = f2bf(c3w[i]); return; }
  i -= 262144;
  if (i < 32256) {    // OWt[(r*9+k)*512 + c] = outw[r*4608 + c*9 + k]
    int c = i & 511, rk = i >> 9;
    int r = rk / 9, k = rk - 9 * r;
    OWt[i] = outw[r * 4608 + c * 9 + k];
  }
}

// ---- init pred with output bias (atomics accumulate partials onto it) -------
__global__ void k_pinit(const float* outb, float* pred) {
  int i = blockIdx.x * 256 + threadIdx.x;
  if (i < 114240) pred[i] = outb[i % 7];
}

// ---- build X0, padded layout [12 + nl*12 + k][512], 4-ch vectorized ---------
__global__ void k_x0(const int* x, const float* emb, unsigned short* X, int n0) {
  int idx = blockIdx.x * 256 + threadIdx.x;
  int c4 = idx & 127, nl = idx >> 7;
  int gn = n0 + nl, b = gn >> 11, w = gn & 2047;
  unsigned short* dst = X + (size_t)(12 + nl * 12) * 512 + (c4 << 2);
  const int* xb = x + (b << 11);
  #pragma unroll
  for (int k = 0; k < 9; k++) {
    int t = w + k; if (t > 2047) t = 2047;
    const float* e = emb + xb[t] * 512 + (c4 << 2);
    float4 ev = *(const float4*)e;
    usv4 pk;
    pk[0] = f2bf(ev.x); pk[1] = f2bf(ev.y);
    pk[2] = f2bf(ev.z); pk[3] = f2bf(ev.w);
    *(usv4*)(dst + k * 512) = pk;
  }
}

// ---- zero leading 12 pad rows of AL (conv tap shifts read rows 10-11) -------
__global__ void k_zpad(unsigned short* AL) {
  int i = threadIdx.x;
  for (; i < 12 * 256; i += 256) AL[i] = 0;
}

// ---- GEMM (MODE 0/1): tile 256(M) x 288(N=32 win), BK=64, 8 waves, dbuf ------
// MODE 0: A=W1b[256][512]  B=X w/ in-LDS inorm1+gelu   epi: inorm2+gelu->AL
// MODE 1: A=W2t[5][256][256] B=AL (tap rows, kb-major) epi: inorm3+gelu->AL2
template <int MODE>
__global__ __launch_bounds__(512, 2) void k_gemm(
    const unsigned short* __restrict__ Aw, const unsigned short* __restrict__ Bsrc,
    const float* __restrict__ n1w, const float* __restrict__ n1b,
    const float* __restrict__ gw, const float* __restrict__ gb,
    unsigned short* __restrict__ Out, int nkc) {
  // [A0 32K][A1 32K][B0 36K][B1 36K] bytes = 136 KB; epilogue sE reuses front
  __shared__ __align__(16) unsigned short smem[69632];
  unsigned short* sE = smem;                  // [288 col][CHP ch]

  const int KROW = (MODE == 0) ? 512 : 256;
  const int KSTEPS = (MODE == 1) ? 20 : 8;
  int tid = threadIdx.x, wv = tid >> 6, ln = tid & 63;
  int lr = ln >> 3, lu = ln & 7;
  int swz = (lu ^ lr) << 3;                   // staging src swizzle (elems)
  int w0 = blockIdx.x << 5;                   // first window of block
  int col0 = blockIdx.x * 288;

  int brow[5];
  #pragma unroll
  for (int s = 0; s < 5; s++) {
    int colg = col0 + (s << 6) + (wv << 3) + lr;
    if (colg >= nkc) colg = nkc - 1;
    brow[s] = colg + 3 * div9(colg) + 12;
  }

  f32x4 acc[4][9];
  #pragma unroll
  for (int i = 0; i < 4; i++)
    #pragma unroll
    for (int j = 0; j < 9; j++) acc[i][j] = (f32x4){0.f, 0.f, 0.f, 0.f};

  auto stage = [&](int buf, int ks) {
    int kb, dlt; const unsigned short* Ab;
    if (MODE == 1) {   // kb-major, tap-minor: 5 consecutive steps share B rows
      int t = ks % 5; kb = (ks / 5) << 6; dlt = t - 2; Ab = Aw + t * 65536;
    } else { kb = ks << 6; dlt = 0; Ab = Aw; }
    unsigned short* cA = smem + buf * 16384;
    unsigned short* cB = smem + 32768 + buf * 18432;
    #pragma unroll
    for (int p = 0; p < 4; p++) {
      int m = (p << 6) + (wv << 3) + lr;
      gload16(Ab + (size_t)m * KROW + kb + swz, cA + (p << 12) + (wv << 9));
    }
    #pragma unroll
    for (int s = 0; s < 4; s++)
      gload16(Bsrc + (size_t)(brow[s] + dlt) * KROW + kb + swz,
              cB + (s << 12) + (wv << 9));
    if (wv < 4)
      gload16(Bsrc + (size_t)(brow[4] + dlt) * KROW + kb + swz,
              cB + (4 << 12) + (wv << 9));
  };

  stage(0, 0);
  __syncthreads();

  int cur = 0;
  for (int ks = 0; ks < KSTEPS; ks++) {
    unsigned short* cA = smem + cur * 16384;
    unsigned short* cB = smem + 32768 + cur * 18432;

    if (MODE == 0) {   // in-LDS inorm1+gelu on staged X slice (4-ch vector)
      int cg = tid & 15, win = tid >> 4;      // 16 ch-groups x 32 windows
      int u = cg >> 1, sub = (cg & 1) << 3;
      int gch = (ks << 6) + (cg << 2);
      float v[9][4], s1[4] = {0.f, 0.f, 0.f, 0.f};
      #pragma unroll
      for (int k = 0; k < 9; k++) {
        int cl = win * 9 + k;
        usv4 rv = *(const usv4*)((char*)cB + cl * 128 + ((u ^ (cl & 7)) << 4) + sub);
        #pragma unroll
        for (int j = 0; j < 4; j++) { v[k][j] = bf2f(rv[j]); s1[j] += v[k][j]; }
      }
      float mn[4], rr[4], gg[4], bo[4];
      #pragma unroll
      for (int j = 0; j < 4; j++) {
        mn[j] = s1[j] * (1.0f / 9.0f);
        float q = 0.f;
        #pragma unroll
        for (int k = 0; k < 9; k++) { float d = v[k][j] - mn[j]; q += d * d; }
        rr[j] = rsqrtf(q * (1.0f / 9.0f) + 1e-5f);
        gg[j] = n1w[gch + j]; bo[j] = n1b[gch + j];
      }
      #pragma unroll
      for (int k = 0; k < 9; k++) {
        int cl = win * 9 + k;
        usv4 pk;
        #pragma unroll
        for (int j = 0; j < 4; j++)
          pk[j] = f2bf(gelu_(gg[j] * (v[k][j] - mn[j]) * rr[j] + bo[j]));
        *(usv4*)((char*)cB + cl * 128 + ((u ^ (cl & 7)) << 4) + sub) = pk;
      }
      __syncthreads();
    }

    if (ks + 1 < KSTEPS) stage(cur ^ 1, ks + 1);   // overlap with MFMA below

    int l16 = ln & 15, loct = ln >> 4;
    int wm = wv >> 1, wn = wv & 1;
    #pragma unroll
    for (int kk = 0; kk < 2; kk++) {
      int kbyte = (kk << 6) + (loct << 4);
      bfv8 af[4], bf_[9];
      #pragma unroll
      for (int mi = 0; mi < 4; mi++) {
        int row = (wm << 6) + (mi << 4) + l16;
        af[mi] = *(const bfv8*)((const char*)cA + row * 128 + (kbyte ^ ((row & 7) << 4)));
      }
      #pragma unroll
      for (int ni = 0; ni < 9; ni++) {
        int row = wn * 144 + (ni << 4) + l16;
        bf_[ni] = *(const bfv8*)((const char*)cB + row * 128 + (kbyte ^ ((row & 7) << 4)));
      }
      #pragma unroll
      for (int mi = 0; mi < 4; mi++)
        #pragma unroll
        for (int ni = 0; ni < 9; ni++)
          acc[mi][ni] = __builtin_amdgcn_mfma_f32_16x16x32_bf16(
              af[mi], bf_[ni], acc[mi][ni], 0, 0, 0);
    }
    __syncthreads();
    cur ^= 1;
  }

  // ---- fused epilogue: 2 rounds of 128 channels, col-major sE ----------------
  int l16 = ln & 15, loct = ln >> 4;
  #pragma unroll
  for (int R = 0; R < 2; R++) {
    if (R) __syncthreads();
    if ((wv >> 2) == R) {
      int chh = (((wv >> 1) & 1) << 6) + (loct << 2);
      int colb = (wv & 1) * 144 + l16;
      #pragma unroll
      for (int mi = 0; mi < 4; mi++) {
        #pragma unroll
        for (int ni = 0; ni < 9; ni++) {
          usv4 pk;
          #pragma unroll
          for (int q = 0; q < 4; q++) pk[q] = f2bf(acc[mi][ni][q]);
          *(usv4*)(sE + (colb + (ni << 4)) * CHP + chh + (mi << 4)) = pk;
        }
      }
    }
    __syncthreads();
    #pragma unroll
    for (int tt = 0; tt < 2; tt++) {
      int t = tid + tt * 512;                 // 1024 tasks: 32 chgrp x 32 win
      int c4 = t & 31, win = t >> 5;
      int chl = (R << 7) + (c4 << 2);
      const unsigned short* sb = sE + (win * 9) * CHP + (c4 << 2);
      size_t ob = (size_t)(12 + (size_t)(w0 + win) * 12) * 256 + chl;
      float s1[4] = {0.f, 0.f, 0.f, 0.f}, s2[4] = {0.f, 0.f, 0.f, 0.f};
      #pragma unroll
      for (int k = 0; k < 9; k++) {
        usv4 rv = *(const usv4*)(sb + k * CHP);
        #pragma unroll
        for (int j = 0; j < 4; j++) {
          float f = bf2f(rv[j]);
          s1[j] += f; s2[j] = __builtin_fmaf(f, f, s2[j]);
        }
      }
      float mn[4], rr[4], gg[4], bo[4];
      #pragma unroll
      for (int j = 0; j < 4; j++) {
        mn[j] = s1[j] * (1.0f / 9.0f);
        float var = s2[j] * (1.0f / 9.0f) - mn[j] * mn[j];
        rr[j] = rsqrtf(var + 1e-5f);
        gg[j] = gw[chl + j]; bo[j] = gb[chl + j];
      }
      #pragma unroll
      for (int k = 0; k < 9; k++) {
        usv4 rv = *(const usv4*)(sb + k * CHP);
        usv4 pk;
        #pragma unroll
        for (int j = 0; j < 4; j++)
          pk[j] = f2bf(gelu_(gg[j] * (bf2f(rv[j]) - mn[j]) * rr[j] + bo[j]));
        *(usv4*)(Out + ob + k * 256) = pk;
      }
      if (MODE == 0) {   // zero window pad rows for conv tap shifts
        usv4 z = (usv4){0, 0, 0, 0};
        *(usv4*)(Out + ob + 9 * 256) = z;
        *(usv4*)(Out + ob + 10 * 256) = z;
        *(usv4*)(Out + ob + 11 * 256) = z;
      }
    }
  }
}

// ---- GEMM c3: tile 128(M) x 144(N=16 win), BK=64, 4 waves, dbuf --------------
// 1-D grid, XCD-aware slab decode. FOUT (last layer): skip X write; dot newX
// against OWt, 16-lane shuffle reduce, one atomicAdd per (win,r) per round.
template <bool FOUT>
__global__ __launch_bounds__(256, 2) void k_gemm2(
    const unsigned short* __restrict__ Aw, const unsigned short* __restrict__ Bsrc,
    const float* __restrict__ cbias, unsigned short* __restrict__ Out, int nkc,
    const float* __restrict__ OWt, float* __restrict__ pred, int n0) {
  __shared__ __align__(16) unsigned short smem[34816];
  unsigned short* sE = smem;

  const int KROW = 256, KSTEPS = 4;
  int tid = threadIdx.x, wv = tid >> 6, ln = tid & 63;
  int lr = ln >> 3, lu = ln & 7;
  int swz = (lu ^ lr) << 3;
  int id = blockIdx.x;
  int slab = (id >> 3) & 3;                   // M-slab 0..3
  int tile = ((id >> 5) << 3) | (id & 7);     // col-tile (tiles % 8 == 0)
  int m0 = slab << 7;
  int w0 = tile << 4;
  int col0 = tile * 144;

  int brow[5];
  #pragma unroll
  for (int s = 0; s < 5; s++) {
    int cl = (s < 4) ? ((s << 5) + (wv << 3) + lr) : (128 + (wv << 3) + lr);
    int colg = col0 + cl;
    if (colg >= nkc) colg = nkc - 1;
    brow[s] = colg + 3 * div9(colg) + 12;
  }
  const unsigned short* A0 = Aw + (size_t)m0 * KROW;

  f32x4 acc[2][9];
  #pragma unroll
  for (int i = 0; i < 2; i++)
    #pragma unroll
    for (int j = 0; j < 9; j++) acc[i][j] = (f32x4){0.f, 0.f, 0.f, 0.f};

  auto stage = [&](int buf, int ks) {
    int kb = ks << 6;
    unsigned short* cA = smem + buf * 8192;
    unsigned short* cB = smem + 16384 + buf * 9216;
    #pragma unroll
    for (int p = 0; p < 4; p++) {
      int m = (p << 5) + (wv << 3) + lr;
      gload16(A0 + (size_t)m * KROW + kb + swz, cA + ((p << 5) + (wv << 3)) * 64);
    }
    #pragma unroll
    for (int s = 0; s < 4; s++)
      gload16(Bsrc + (size_t)brow[s] * KROW + kb + swz,
              cB + ((s << 5) + (wv << 3)) * 64);
    if (wv < 2)
      gload16(Bsrc + (size_t)brow[4] * KROW + kb + swz,
              cB + (128 + (wv << 3)) * 64);
  };

  stage(0, 0);
  __syncthreads();

  int cur = 0;
  for (int ks = 0; ks < KSTEPS; ks++) {
    unsigned short* cA = smem + cur * 8192;
    unsigned short* cB = smem + 16384 + cur * 9216;
    if (ks + 1 < KSTEPS) stage(cur ^ 1, ks + 1);

    int l16 = ln & 15, loct = ln >> 4;
    #pragma unroll
    for (int kk = 0; kk < 2; kk++) {
      int kbyte = (kk << 6) + (loct << 4);
      bfv8 af[2], bf_[9];
      #pragma unroll
      for (int mi = 0; mi < 2; mi++) {
        int row = (wv << 5) + (mi << 4) + l16;
        af[mi] = *(const bfv8*)((const char*)cA + row * 128 + (kbyte ^ ((row & 7) << 4)));
      }
      #pragma unroll
      for (int ni = 0; ni < 9; ni++) {
        int row = (ni << 4) + l16;
        bf_[ni] = *(const bfv8*)((const char*)cB + row * 128 + (kbyte ^ ((row & 7) << 4)));
      }
      #pragma unroll
      for (int mi = 0; mi < 2; mi++)
        #pragma unroll
        for (int ni = 0; ni < 9; ni++)
          acc[mi][ni] = __builtin_amdgcn_mfma_f32_16x16x32_bf16(
              af[mi], bf_[ni], acc[mi][ni], 0, 0, 0);
    }
    __syncthreads();
    cur ^= 1;
  }

  int l16 = ln & 15, loct = ln >> 4;
  int c4 = tid & 15, win = tid >> 4;
  #pragma unroll
  for (int R = 0; R < 2; R++) {
    if (R) __syncthreads();
    if ((wv >> 1) == R) {
      int chh = ((wv & 1) << 5) + (loct << 2);
      #pragma unroll
      for (int mi = 0; mi < 2; mi++) {
        #pragma unroll
        for (int ni = 0; ni < 9; ni++) {
          usv4 pk;
          #pragma unroll
          for (int q = 0; q < 4; q++) pk[q] = f2bf(acc[mi][ni][q]);
          *(usv4*)(sE + ((ni << 4) + l16) * CHP2 + chh + (mi << 4)) = pk;
        }
      }
    }
    __syncthreads();
    {
      int chg = m0 + (R << 6) + (c4 << 2);
      const unsigned short* sb = sE + (win * 9) * CHP2 + (c4 << 2);
      size_t ob = (size_t)(12 + (size_t)(w0 + win) * 12) * 512 + chg;
      float cb[4];
      #pragma unroll
      for (int j = 0; j < 4; j++) cb[j] = cbias[chg + j];
      if (!FOUT) {
        #pragma unroll
        for (int k = 0; k < 9; k++) {
          usv4 rv = *(const usv4*)(sb + k * CHP2);
          usv4 old = *(usv4*)(Out + ob + k * 512);
          usv4 pk;
          #pragma unroll
          for (int j = 0; j < 4; j++)
            pk[j] = f2bf(bf2f(rv[j]) + cb[j] + bf2f(old[j]));
          *(usv4*)(Out + ob + k * 512) = pk;
        }
      } else {
        float v[9][4];
        #pragma unroll
        for (int k = 0; k < 9; k++) {
          usv4 rv = *(const usv4*)(sb + k * CHP2);
          usv4 old = *(usv4*)(Out + ob + k * 512);
          #pragma unroll
          for (int j = 0; j < 4; j++)
            v[k][j] = bf2f(rv[j]) + cb[j] + bf2f(old[j]);
        }
        int gn = n0 + w0 + win, b = gn >> 11, w = gn & 2047;
        #pragma unroll
        for (int r = 0; r < 7; r++) {
          float p = 0.f;
          #pragma unroll
          for (int k = 0; k < 9; k++) {
            const float* wp = OWt + (r * 9 + k) * 512 + chg;
            float4 wvv = *(const float4*)wp;
            p = __builtin_fmaf(v[k][0], wvv.x, p);
            p = __builtin_fmaf(v[k][1], wvv.y, p);
            p = __builtin_fmaf(v[k][2], wvv.z, p);
            p = __builtin_fmaf(v[k][3], wvv.w, p);
          }
          p += __shfl_xor(p, 1);
          p += __shfl_xor(p, 2);
          p += __shfl_xor(p, 4);
          p += __shfl_xor(p, 8);
          if (c4 == 0 && w < 2040)
            atomicAdd(pred + (size_t)(b * 2040 + w) * 7 + r, p);
        }
      }
    }
  }
}

extern "C" void kernel_launch(void* const* d_in, const int* in_sizes, int n_in,
                              void* d_out, int out_size, void* d_ws, size_t ws_size,
                              hipStream_t stream) {
  const int*   x    = (const int*)d_in[0];
  const float* emb  = (const float*)d_in[1];
  const float* ln1w = (const float*)d_in[2];
  const float* ln1b = (const float*)d_in[3];
  const float* ln2w = (const float*)d_in[4];
  const float* ln2b = (const float*)d_in[5];
  const float* ln3w = (const float*)d_in[6];
  const float* ln3b = (const float*)d_in[7];
  const float* c1w  = (const float*)d_in[8];
  const float* c2w  = (const float*)d_in[10];
  const float* c3w  = (const float*)d_in[12];
  const float* c3b  = (const float*)d_in[13];
  const float* outw = (const float*)d_in[14];
  const float* outb = (const float*)d_in[15];
  float* pred = (float*)d_out;

  // cap nc at 8192 (ws limit / LLC residency)
  int nc = 8192;
  while (nc > 128 &&
         2488320ull + (unsigned long long)(nc + 1) * 24576ull > ws_size)
    nc >>= 1;
  int nkc = nc * 9;
  int tiles288 = nc >> 5;              // 288-col tiles (MODE 0/1)
  int tiles144 = nc >> 4;              // 144-col tiles (gemm2)
  int nchunks = 16384 / nc;

  char* ws = (char*)d_ws;
  unsigned short* W1b = (unsigned short*)(ws);
  unsigned short* W2t = (unsigned short*)(ws + 524288);
  unsigned short* W3b = (unsigned short*)(ws + 1835008);
  float*          OWt = (float*)(ws + 2359296);
  char* act = ws + 2488320;
  size_t hiB = (size_t)(nc + 1) * 12288;
  size_t loB = (size_t)(nc + 1) * 6144;
  unsigned short* X   = (unsigned short*)(act);
  unsigned short* AL  = (unsigned short*)(act + hiB);
  unsigned short* AL2 = (unsigned short*)(act + hiB + loB);

  k_prep<<<(1211904 + 255) / 256, 256, 0, stream>>>(c1w, c2w, c3w, outw,
                                                    W1b, W2t, W3b, OWt);
  k_zpad<<<1, 256, 0, stream>>>(AL);
  k_pinit<<<(114240 + 255) / 256, 256, 0, stream>>>(outb, pred);

  for (int ch = 0; ch < nchunks; ch++) {
    int n0 = ch * nc;
    k_x0<<<nc / 2, 256, 0, stream>>>(x, emb, X, n0);
    for (int l = 0; l < 2; l++) {
      k_gemm<0><<<dim3(tiles288, 1), 512, 0, stream>>>(
          W1b + l * 131072, X, ln1w + l * 512, ln1b + l * 512,
          ln2w + l * 256, ln2b + l * 256, AL, nkc);
      k_gemm<1><<<dim3(tiles288, 1), 512, 0, stream>>>(
          W2t + l * 327680, AL, nullptr, nullptr,
          ln3w + l * 256, ln3b + l * 256, AL2, nkc);
      if (l == 0)
        k_gemm2<false><<<tiles144 * 4, 256, 0, stream>>>(
            W3b, AL2, c3b, X, nkc, nullptr, nullptr, 0);
      else
        k_gemm2<true><<<tiles144 * 4, 256, 0, stream>>>(
            W3b + 131072, AL2, c3b + 512, X, nkc, OWt, pred, n0);
    }
  }
}

// Round 21
// 716.834 us; speedup vs baseline: 1.4573x; 1.0566x over previous
//
#include <hip/hip_runtime.h>

typedef __attribute__((ext_vector_type(8))) short bfv8;
typedef __attribute__((ext_vector_type(4))) float f32x4;
typedef __attribute__((ext_vector_type(4))) unsigned short usv4;

typedef __attribute__((address_space(1))) const void gvoid;
typedef __attribute__((address_space(3))) void lvoid;
__device__ __forceinline__ void gload16(const void* g, void* l) {
  __builtin_amdgcn_global_load_lds((gvoid*)g, (lvoid*)l, 16, 0, 0);
}

__device__ __forceinline__ float bf2f(unsigned short u) {
  union { unsigned int i; float f; } c; c.i = ((unsigned int)u) << 16; return c.f;
}
__device__ __forceinline__ unsigned short f2bf(float f) {
  union { float f; unsigned int i; } c; c.f = f;
  unsigned int r = c.i + 0x7FFFu + ((c.i >> 16) & 1u);
  return (unsigned short)(r >> 16);
}
// tanh-form gelu via hw exp+rcp (max dev from erf-gelu ~5e-4)
__device__ __forceinline__ float gelu_(float x) {
  float z2 = 1.5957691216057308f * x * __builtin_fmaf(0.044715f, x * x, 1.0f);
  float e = __expf(z2);
  float t = __builtin_amdgcn_rcpf(e + 1.0f);
  return x - x * t;
}
__device__ __forceinline__ int div9(int col) {
  return (int)(__umulhi((unsigned)col, 954437177u) >> 1);
}

#define CHP 132   // big-kernel epilogue LDS channel stride (u16)
#define CHP2 66   // gemm2 kernel epilogue stride

// ---- weight prep ------------------------------------------------------------
__global__ void k_prep(const float* c1w, const float* c2w, const float* c3w,
                       const float* outw, unsigned short* W1b, unsigned short* W2t,
                       unsigned short* W3b, float* OWt) {
  int i = blockIdx.x * 256 + threadIdx.x;
  if (i < 262144) { W1b[i] = f2bf(c1w[i]); return; }
  i -= 262144;
  if (i < 655360) {   // W2t[l][t][o][ii] = c2w[l][o][ii][t]
    int ii = i & 255, o = (i >> 8) & 255, rest = i >> 16;
    int t = rest % 5, l = rest / 5;
    W2t[i] = f2bf(c2w[(((l * 256 + o) << 8) + ii) * 5 + t]);
    return;
  }
  i -= 655360;
  if (i < 262144) { W3b[i] = f2bf(c3w[i]); return; }
  i -= 262144;
  if (i < 32256) {    // OWt[(r*9+k)*512 + c] = outw[r*4608 + c*9 + k]
    int c = i & 511, rk = i >> 9;
    int r = rk / 9, k = rk - 9 * r;
    OWt[i] = outw[r * 4608 + c * 9 + k];
  }
}

// ---- init pred with output bias (atomics accumulate partials onto it) -------
__global__ void k_pinit(const float* outb, float* pred) {
  int i = blockIdx.x * 256 + threadIdx.x;
  if (i < 114240) pred[i] = outb[i % 7];
}

// ---- build X0, padded layout [12 + nl*12 + k][512], 4-ch vectorized ---------
__global__ void k_x0(const int* x, const float* emb, unsigned short* X, int n0) {
  int idx = blockIdx.x * 256 + threadIdx.x;
  int c4 = idx & 127, nl = idx >> 7;
  int gn = n0 + nl, b = gn >> 11, w = gn & 2047;
  unsigned short* dst = X + (size_t)(12 + nl * 12) * 512 + (c4 << 2);
  const int* xb = x + (b << 11);
  #pragma unroll
  for (int k = 0; k < 9; k++) {
    int t = w + k; if (t > 2047) t = 2047;
    const float* e = emb + xb[t] * 512 + (c4 << 2);
    float4 ev = *(const float4*)e;
    usv4 pk;
    pk[0] = f2bf(ev.x); pk[1] = f2bf(ev.y);
    pk[2] = f2bf(ev.z); pk[3] = f2bf(ev.w);
    *(usv4*)(dst + k * 512) = pk;
  }
}

// ---- zero leading 12 pad rows of AL (conv tap shifts read rows 10-11) -------
__global__ void k_zpad(unsigned short* AL) {
  int i = threadIdx.x;
  for (; i < 12 * 256; i += 256) AL[i] = 0;
}

// ---- GEMM (MODE 0/1): tile 256(M) x 288(N=32 win), BK=64, 8 waves, dbuf ------
// MODE 0: A=W1b[256][512]  B=X w/ in-LDS inorm1+gelu   epi: inorm2+gelu->AL
// MODE 1: A=W2t[5][256][256] B=AL (tap rows, kb-major) epi: inorm3+gelu->AL2
template <int MODE>
__global__ __launch_bounds__(512, 2) void k_gemm(
    const unsigned short* __restrict__ Aw, const unsigned short* __restrict__ Bsrc,
    const float* __restrict__ n1w, const float* __restrict__ n1b,
    const float* __restrict__ gw, const float* __restrict__ gb,
    unsigned short* __restrict__ Out, int nkc) {
  // [A0 32K][A1 32K][B0 36K][B1 36K] bytes = 136 KB; epilogue sE reuses front
  __shared__ __align__(16) unsigned short smem[69632];
  unsigned short* sE = smem;                  // [288 col][CHP ch]

  const int KROW = (MODE == 0) ? 512 : 256;
  const int KSTEPS = (MODE == 1) ? 20 : 8;
  int tid = threadIdx.x, wv = tid >> 6, ln = tid & 63;
  int lr = ln >> 3, lu = ln & 7;
  int swz = (lu ^ lr) << 3;                   // staging src swizzle (elems)
  int w0 = blockIdx.x << 5;                   // first window of block
  int col0 = blockIdx.x * 288;

  int brow[5];
  #pragma unroll
  for (int s = 0; s < 5; s++) {
    int colg = col0 + (s << 6) + (wv << 3) + lr;
    if (colg >= nkc) colg = nkc - 1;
    brow[s] = colg + 3 * div9(colg) + 12;
  }

  f32x4 acc[4][9];
  #pragma unroll
  for (int i = 0; i < 4; i++)
    #pragma unroll
    for (int j = 0; j < 9; j++) acc[i][j] = (f32x4){0.f, 0.f, 0.f, 0.f};

  auto stage = [&](int buf, int ks) {
    int kb, dlt; const unsigned short* Ab;
    if (MODE == 1) {   // kb-major, tap-minor: 5 consecutive steps share B rows
      int t = ks % 5; kb = (ks / 5) << 6; dlt = t - 2; Ab = Aw + t * 65536;
    } else { kb = ks << 6; dlt = 0; Ab = Aw; }
    unsigned short* cA = smem + buf * 16384;
    unsigned short* cB = smem + 32768 + buf * 18432;
    #pragma unroll
    for (int p = 0; p < 4; p++) {
      int m = (p << 6) + (wv << 3) + lr;
      gload16(Ab + (size_t)m * KROW + kb + swz, cA + (p << 12) + (wv << 9));
    }
    #pragma unroll
    for (int s = 0; s < 4; s++)
      gload16(Bsrc + (size_t)(brow[s] + dlt) * KROW + kb + swz,
              cB + (s << 12) + (wv << 9));
    if (wv < 4)
      gload16(Bsrc + (size_t)(brow[4] + dlt) * KROW + kb + swz,
              cB + (4 << 12) + (wv << 9));
  };

  stage(0, 0);
  __syncthreads();

  int cur = 0;
  for (int ks = 0; ks < KSTEPS; ks++) {
    unsigned short* cA = smem + cur * 16384;
    unsigned short* cB = smem + 32768 + cur * 18432;

    if (MODE == 0) {   // in-LDS inorm1+gelu on staged X slice (4-ch vector)
      int cg = tid & 15, win = tid >> 4;      // 16 ch-groups x 32 windows
      int u = cg >> 1, sub = (cg & 1) << 3;
      int gch = (ks << 6) + (cg << 2);
      float v[9][4], s1[4] = {0.f, 0.f, 0.f, 0.f};
      #pragma unroll
      for (int k = 0; k < 9; k++) {
        int cl = win * 9 + k;
        usv4 rv = *(const usv4*)((char*)cB + cl * 128 + ((u ^ (cl & 7)) << 4) + sub);
        #pragma unroll
        for (int j = 0; j < 4; j++) { v[k][j] = bf2f(rv[j]); s1[j] += v[k][j]; }
      }
      float mn[4], rr[4], gg[4], bo[4];
      #pragma unroll
      for (int j = 0; j < 4; j++) {
        mn[j] = s1[j] * (1.0f / 9.0f);
        float q = 0.f;
        #pragma unroll
        for (int k = 0; k < 9; k++) { float d = v[k][j] - mn[j]; q += d * d; }
        rr[j] = rsqrtf(q * (1.0f / 9.0f) + 1e-5f);
        gg[j] = n1w[gch + j]; bo[j] = n1b[gch + j];
      }
      #pragma unroll
      for (int k = 0; k < 9; k++) {
        int cl = win * 9 + k;
        usv4 pk;
        #pragma unroll
        for (int j = 0; j < 4; j++)
          pk[j] = f2bf(gelu_(gg[j] * (v[k][j] - mn[j]) * rr[j] + bo[j]));
        *(usv4*)((char*)cB + cl * 128 + ((u ^ (cl & 7)) << 4) + sub) = pk;
      }
      __syncthreads();
    }

    if (ks + 1 < KSTEPS) stage(cur ^ 1, ks + 1);   // overlap with MFMA below

    int l16 = ln & 15, loct = ln >> 4;
    int wm = wv >> 1, wn = wv & 1;
    #pragma unroll
    for (int kk = 0; kk < 2; kk++) {
      int kbyte = (kk << 6) + (loct << 4);
      bfv8 af[4], bf_[9];
      #pragma unroll
      for (int mi = 0; mi < 4; mi++) {
        int row = (wm << 6) + (mi << 4) + l16;
        af[mi] = *(const bfv8*)((const char*)cA + row * 128 + (kbyte ^ ((row & 7) << 4)));
      }
      #pragma unroll
      for (int ni = 0; ni < 9; ni++) {
        int row = wn * 144 + (ni << 4) + l16;
        bf_[ni] = *(const bfv8*)((const char*)cB + row * 128 + (kbyte ^ ((row & 7) << 4)));
      }
      #pragma unroll
      for (int mi = 0; mi < 4; mi++)
        #pragma unroll
        for (int ni = 0; ni < 9; ni++)
          acc[mi][ni] = __builtin_amdgcn_mfma_f32_16x16x32_bf16(
              af[mi], bf_[ni], acc[mi][ni], 0, 0, 0);
    }
    __syncthreads();
    cur ^= 1;
  }

  // ---- fused epilogue: 2 rounds of 128 channels, col-major sE ----------------
  int l16 = ln & 15, loct = ln >> 4;
  #pragma unroll
  for (int R = 0; R < 2; R++) {
    if (R) __syncthreads();
    if ((wv >> 2) == R) {
      int chh = (((wv >> 1) & 1) << 6) + (loct << 2);
      int colb = (wv & 1) * 144 + l16;
      #pragma unroll
      for (int mi = 0; mi < 4; mi++) {
        #pragma unroll
        for (int ni = 0; ni < 9; ni++) {
          usv4 pk;
          #pragma unroll
          for (int q = 0; q < 4; q++) pk[q] = f2bf(acc[mi][ni][q]);
          *(usv4*)(sE + (colb + (ni << 4)) * CHP + chh + (mi << 4)) = pk;
        }
      }
    }
    __syncthreads();
    #pragma unroll
    for (int tt = 0; tt < 2; tt++) {
      int t = tid + tt * 512;                 // 1024 tasks: 32 chgrp x 32 win
      int c4 = t & 31, win = t >> 5;
      int chl = (R << 7) + (c4 << 2);
      const unsigned short* sb = sE + (win * 9) * CHP + (c4 << 2);
      size_t ob = (size_t)(12 + (size_t)(w0 + win) * 12) * 256 + chl;
      float s1[4] = {0.f, 0.f, 0.f, 0.f}, s2[4] = {0.f, 0.f, 0.f, 0.f};
      #pragma unroll
      for (int k = 0; k < 9; k++) {
        usv4 rv = *(const usv4*)(sb + k * CHP);
        #pragma unroll
        for (int j = 0; j < 4; j++) {
          float f = bf2f(rv[j]);
          s1[j] += f; s2[j] = __builtin_fmaf(f, f, s2[j]);
        }
      }
      float mn[4], rr[4], gg[4], bo[4];
      #pragma unroll
      for (int j = 0; j < 4; j++) {
        mn[j] = s1[j] * (1.0f / 9.0f);
        float var = s2[j] * (1.0f / 9.0f) - mn[j] * mn[j];
        rr[j] = rsqrtf(var + 1e-5f);
        gg[j] = gw[chl + j]; bo[j] = gb[chl + j];
      }
      #pragma unroll
      for (int k = 0; k < 9; k++) {
        usv4 rv = *(const usv4*)(sb + k * CHP);
        usv4 pk;
        #pragma unroll
        for (int j = 0; j < 4; j++)
          pk[j] = f2bf(gelu_(gg[j] * (bf2f(rv[j]) - mn[j]) * rr[j] + bo[j]));
        *(usv4*)(Out + ob + k * 256) = pk;
      }
      if (MODE == 0) {   // zero window pad rows for conv tap shifts
        usv4 z = (usv4){0, 0, 0, 0};
        *(usv4*)(Out + ob + 9 * 256) = z;
        *(usv4*)(Out + ob + 10 * 256) = z;
        *(usv4*)(Out + ob + 11 * 256) = z;
      }
    }
  }
}

// ---- GEMM c3: tile 128(M) x 144(N=16 win), BK=64, 4 waves, dbuf --------------
// 1-D grid, XCD-aware slab decode. FOUT (last layer): skip X write; OWt slab
// staged to LDS, dot newX against it, 16-lane shuffle reduce, one atomicAdd.
template <bool FOUT>
__global__ __launch_bounds__(256, 2) void k_gemm2(
    const unsigned short* __restrict__ Aw, const unsigned short* __restrict__ Bsrc,
    const float* __restrict__ cbias, unsigned short* __restrict__ Out, int nkc,
    const float* __restrict__ OWt, float* __restrict__ pred, int n0) {
  __shared__ __align__(16) unsigned short smem[34816];
  unsigned short* sE = smem;                         // [144][CHP2] = 19008 B
  float* owl = (float*)((char*)smem + 19008);        // OWt slab: 63x128 f32

  const int KROW = 256, KSTEPS = 4;
  int tid = threadIdx.x, wv = tid >> 6, ln = tid & 63;
  int lr = ln >> 3, lu = ln & 7;
  int swz = (lu ^ lr) << 3;
  int id = blockIdx.x;
  int slab = (id >> 3) & 3;                   // M-slab 0..3
  int tile = ((id >> 5) << 3) | (id & 7);     // col-tile (tiles % 8 == 0)
  int m0 = slab << 7;
  int w0 = tile << 4;
  int col0 = tile * 144;

  int brow[5];
  #pragma unroll
  for (int s = 0; s < 5; s++) {
    int cl = (s < 4) ? ((s << 5) + (wv << 3) + lr) : (128 + (wv << 3) + lr);
    int colg = col0 + cl;
    if (colg >= nkc) colg = nkc - 1;
    brow[s] = colg + 3 * div9(colg) + 12;
  }
  const unsigned short* A0 = Aw + (size_t)m0 * KROW;

  f32x4 acc[2][9];
  #pragma unroll
  for (int i = 0; i < 2; i++)
    #pragma unroll
    for (int j = 0; j < 9; j++) acc[i][j] = (f32x4){0.f, 0.f, 0.f, 0.f};

  auto stage = [&](int buf, int ks) {
    int kb = ks << 6;
    unsigned short* cA = smem + buf * 8192;
    unsigned short* cB = smem + 16384 + buf * 9216;
    #pragma unroll
    for (int p = 0; p < 4; p++) {
      int m = (p << 5) + (wv << 3) + lr;
      gload16(A0 + (size_t)m * KROW + kb + swz, cA + ((p << 5) + (wv << 3)) * 64);
    }
    #pragma unroll
    for (int s = 0; s < 4; s++)
      gload16(Bsrc + (size_t)brow[s] * KROW + kb + swz,
              cB + ((s << 5) + (wv << 3)) * 64);
    if (wv < 2)
      gload16(Bsrc + (size_t)brow[4] * KROW + kb + swz,
              cB + (128 + (wv << 3)) * 64);
  };

  stage(0, 0);
  __syncthreads();

  int cur = 0;
  for (int ks = 0; ks < KSTEPS; ks++) {
    unsigned short* cA = smem + cur * 8192;
    unsigned short* cB = smem + 16384 + cur * 9216;
    if (ks + 1 < KSTEPS) stage(cur ^ 1, ks + 1);

    int l16 = ln & 15, loct = ln >> 4;
    #pragma unroll
    for (int kk = 0; kk < 2; kk++) {
      int kbyte = (kk << 6) + (loct << 4);
      bfv8 af[2], bf_[9];
      #pragma unroll
      for (int mi = 0; mi < 2; mi++) {
        int row = (wv << 5) + (mi << 4) + l16;
        af[mi] = *(const bfv8*)((const char*)cA + row * 128 + (kbyte ^ ((row & 7) << 4)));
      }
      #pragma unroll
      for (int ni = 0; ni < 9; ni++) {
        int row = (ni << 4) + l16;
        bf_[ni] = *(const bfv8*)((const char*)cB + row * 128 + (kbyte ^ ((row & 7) << 4)));
      }
      #pragma unroll
      for (int mi = 0; mi < 2; mi++)
        #pragma unroll
        for (int ni = 0; ni < 9; ni++)
          acc[mi][ni] = __builtin_amdgcn_mfma_f32_16x16x32_bf16(
              af[mi], bf_[ni], acc[mi][ni], 0, 0, 0);
    }
    __syncthreads();
    cur ^= 1;
  }

  // FOUT: stage this slab's OWt rows (63 x 128 f32 = 32256 B) into LDS.
  // cA/cB are dead (k-loop done + barrier); dest above sE (19008..51264 B).
  if (FOUT) {
    #pragma unroll
    for (int i = 0; i < 8; i++) {
      int c = (i << 8) + tid;                 // 16B chunk id, 0..2015
      if (c < 2016)
        gload16(OWt + (size_t)(c >> 5) * 512 + m0 + ((c & 31) << 2),
                (char*)owl + c * 16);
    }
  }

  int l16 = ln & 15, loct = ln >> 4;
  int c4 = tid & 15, win = tid >> 4;
  #pragma unroll
  for (int R = 0; R < 2; R++) {
    if (R) __syncthreads();
    if ((wv >> 1) == R) {
      int chh = ((wv & 1) << 5) + (loct << 2);
      #pragma unroll
      for (int mi = 0; mi < 2; mi++) {
        #pragma unroll
        for (int ni = 0; ni < 9; ni++) {
          usv4 pk;
          #pragma unroll
          for (int q = 0; q < 4; q++) pk[q] = f2bf(acc[mi][ni][q]);
          *(usv4*)(sE + ((ni << 4) + l16) * CHP2 + chh + (mi << 4)) = pk;
        }
      }
    }
    __syncthreads();   // also drains OWt staging vmcnt (R=0)
    {
      int chg = m0 + (R << 6) + (c4 << 2);
      const unsigned short* sb = sE + (win * 9) * CHP2 + (c4 << 2);
      size_t ob = (size_t)(12 + (size_t)(w0 + win) * 12) * 512 + chg;
      float cb[4];
      #pragma unroll
      for (int j = 0; j < 4; j++) cb[j] = cbias[chg + j];
      if (!FOUT) {
        #pragma unroll
        for (int k = 0; k < 9; k++) {
          usv4 rv = *(const usv4*)(sb + k * CHP2);
          usv4 old = *(usv4*)(Out + ob + k * 512);
          usv4 pk;
          #pragma unroll
          for (int j = 0; j < 4; j++)
            pk[j] = f2bf(bf2f(rv[j]) + cb[j] + bf2f(old[j]));
          *(usv4*)(Out + ob + k * 512) = pk;
        }
      } else {
        float v[9][4];
        #pragma unroll
        for (int k = 0; k < 9; k++) {
          usv4 rv = *(const usv4*)(sb + k * CHP2);
          usv4 old = *(usv4*)(Out + ob + k * 512);
          #pragma unroll
          for (int j = 0; j < 4; j++)
            v[k][j] = bf2f(rv[j]) + cb[j] + bf2f(old[j]);
        }
        int gn = n0 + w0 + win, b = gn >> 11, w = gn & 2047;
        int cho = (R << 6) + (c4 << 2);       // channel offset within slab
        #pragma unroll
        for (int r = 0; r < 7; r++) {
          float p = 0.f;
          #pragma unroll
          for (int k = 0; k < 9; k++) {
            float4 wvv = *(const float4*)(owl + (r * 9 + k) * 128 + cho);
            p = __builtin_fmaf(v[k][0], wvv.x, p);
            p = __builtin_fmaf(v[k][1], wvv.y, p);
            p = __builtin_fmaf(v[k][2], wvv.z, p);
            p = __builtin_fmaf(v[k][3], wvv.w, p);
          }
          p += __shfl_xor(p, 1);
          p += __shfl_xor(p, 2);
          p += __shfl_xor(p, 4);
          p += __shfl_xor(p, 8);
          if (c4 == 0 && w < 2040)
            atomicAdd(pred + (size_t)(b * 2040 + w) * 7 + r, p);
        }
      }
    }
  }
}

extern "C" void kernel_launch(void* const* d_in, const int* in_sizes, int n_in,
                              void* d_out, int out_size, void* d_ws, size_t ws_size,
                              hipStream_t stream) {
  const int*   x    = (const int*)d_in[0];
  const float* emb  = (const float*)d_in[1];
  const float* ln1w = (const float*)d_in[2];
  const float* ln1b = (const float*)d_in[3];
  const float* ln2w = (const float*)d_in[4];
  const float* ln2b = (const float*)d_in[5];
  const float* ln3w = (const float*)d_in[6];
  const float* ln3b = (const float*)d_in[7];
  const float* c1w  = (const float*)d_in[8];
  const float* c2w  = (const float*)d_in[10];
  const float* c3w  = (const float*)d_in[12];
  const float* c3b  = (const float*)d_in[13];
  const float* outw = (const float*)d_in[14];
  const float* outb = (const float*)d_in[15];
  float* pred = (float*)d_out;

  // cap nc at 8192 (ws limit / LLC residency)
  int nc = 8192;
  while (nc > 128 &&
         2488320ull + (unsigned long long)(nc + 1) * 24576ull > ws_size)
    nc >>= 1;
  int nkc = nc * 9;
  int tiles288 = nc >> 5;              // 288-col tiles (MODE 0/1)
  int tiles144 = nc >> 4;              // 144-col tiles (gemm2)
  int nchunks = 16384 / nc;

  char* ws = (char*)d_ws;
  unsigned short* W1b = (unsigned short*)(ws);
  unsigned short* W2t = (unsigned short*)(ws + 524288);
  unsigned short* W3b = (unsigned short*)(ws + 1835008);
  float*          OWt = (float*)(ws + 2359296);
  char* act = ws + 2488320;
  size_t hiB = (size_t)(nc + 1) * 12288;
  size_t loB = (size_t)(nc + 1) * 6144;
  unsigned short* X   = (unsigned short*)(act);
  unsigned short* AL  = (unsigned short*)(act + hiB);
  unsigned short* AL2 = (unsigned short*)(act + hiB + loB);

  k_prep<<<(1211904 + 255) / 256, 256, 0, stream>>>(c1w, c2w, c3w, outw,
                                                    W1b, W2t, W3b, OWt);
  k_zpad<<<1, 256, 0, stream>>>(AL);
  k_pinit<<<(114240 + 255) / 256, 256, 0, stream>>>(outb, pred);

  for (int ch = 0; ch < nchunks; ch++) {
    int n0 = ch * nc;
    k_x0<<<nc / 2, 256, 0, stream>>>(x, emb, X, n0);
    for (int l = 0; l < 2; l++) {
      k_gemm<0><<<dim3(tiles288, 1), 512, 0, stream>>>(
          W1b + l * 131072, X, ln1w + l * 512, ln1b + l * 512,
          ln2w + l * 256, ln2b + l * 256, AL, nkc);
      k_gemm<1><<<dim3(tiles288, 1), 512, 0, stream>>>(
          W2t + l * 327680, AL, nullptr, nullptr,
          ln3w + l * 256, ln3b + l * 256, AL2, nkc);
      if (l == 0)
        k_gemm2<false><<<tiles144 * 4, 256, 0, stream>>>(
            W3b, AL2, c3b, X, nkc, nullptr, nullptr, 0);
      else
        k_gemm2<true><<<tiles144 * 4, 256, 0, stream>>>(
            W3b + 131072, AL2, c3b + 512, X, nkc, OWt, pred, n0);
    }
  }
}